// Round 4
// baseline (133.026 us; speedup 1.0000x reference)
//
#include <hip/hip_runtime.h>
#include <math.h>

// Problem constants (from reference)
#define NCAMS 48      // B*NC = 8*6
#define NC_   6
#define A_    25200
#define C_    10
#define MAXGT 32
#define L_COORD 5.0f
#define L_NOOBJ 0.5f

// Decomposition: 2 anchors/thread -> 2400 blocks (full residency),
// GT data in SGPRs (uniform s_load), hot loop = 11 VALU ops/pair.
#define BLOCK  256
#define APT    2
#define CHUNK  (BLOCK * APT)                 // 512
#define NCHUNK ((A_ + CHUNK - 1) / CHUNK)    // 50

__device__ __forceinline__ float softplus_f(float x) {
    return fmaxf(x, 0.0f) + log1pf(expf(-fabsf(x)));
}

// ---------------- prep: per (cam,k) GT corners + threshold; per-cam meta ----
// gtprep[cam][k][8]: 0..3 = g1x,g1y,g2x,g2y ; 4 = ga + 1e-6
// gtmeta[cam][2]   : start, ngt
__global__ void yolo_prep(const float* __restrict__ gt_boxes,
                          const int*   __restrict__ se,
                          int total_gt,
                          float* __restrict__ gtprep,
                          int*   __restrict__ gtmeta)
{
    const int t   = blockIdx.x * blockDim.x + threadIdx.x;   // over NCAMS*32
    const int cam = t >> 5;
    const int k   = t & 31;
    if (cam >= NCAMS) return;

    const int b  = cam / NC_;
    const int nc = cam - b * NC_;
    int off = 0;
    for (int bb = 0; bb < b; ++bb) off += se[bb * NC_ + (NC_ - 1)];
    const int start = off + (nc ? se[b * NC_ + nc - 1] : 0);
    const int end   = off + se[b * NC_ + nc];
    int ngt = end - start;
    ngt = min(max(ngt, 0), MAXGT);

    if (k == 0) { gtmeta[cam * 2] = start; gtmeta[cam * 2 + 1] = ngt; }
    float* q = gtprep + (size_t)(cam * MAXGT + k) * 8;
    if (k < ngt) {
        const int gi = min(max(start + k, 0), total_gt - 1);  // reference clips
        const float4 gb = ((const float4*)gt_boxes)[gi];
        const float hw = gb.z * 0.5f, hh = gb.w * 0.5f;
        q[0] = gb.x - hw; q[1] = gb.y - hh;
        q[2] = gb.x + hw; q[3] = gb.y + hh;
        q[4] = gb.z * gb.w + 1e-6f;
    }
}

// ---------------- phase 1 ----------------
__global__ __launch_bounds__(BLOCK)
void yolo_phase1(const float* __restrict__ pred_boxes,   // (cams, A, 4)
                 const float* __restrict__ pred_labels,  // (cams, A, C)
                 const float* __restrict__ pred_obj,     // (cams, A, 1)
                 const float* __restrict__ gt_boxes,     // (TG, 4)
                 const int*   __restrict__ gt_labels,    // (TG)
                 const float* __restrict__ gtprep,
                 const int*   __restrict__ gtmeta,
                 int total_gt,
                 float* __restrict__ partials)           // (cams*NCHUNK, 8)
{
    const int cam   = blockIdx.y;
    const int chunk = blockIdx.x;
    const int tid   = threadIdx.x;

    __shared__ float s_red[BLOCK / 64][6];

    // uniform per block -> scalar loads, no barrier needed
    const int start = gtmeta[cam * 2];
    const int ngt   = gtmeta[cam * 2 + 1];
    const float* __restrict__ gp = gtprep + (size_t)cam * MAXGT * 8;

    const int base = chunk * CHUNK;
    const float4* pb4 = (const float4*)pred_boxes;

    const int a0 = base + tid;
    const int a1 = base + BLOCK + tid;
    const bool v0 = (a0 < A_);
    const bool v1 = (a1 < A_);
    const int idx0 = cam * A_ + (v0 ? a0 : (A_ - 1));
    const int idx1 = cam * A_ + (v1 ? a1 : (A_ - 1));

    const float4 p0 = pb4[idx0];
    const float4 p1 = pb4[idx1];
    const float o0 = pred_obj[idx0];
    const float o1 = pred_obj[idx1];

    const float p1x0 = p0.x - p0.z * 0.5f, p1y0 = p0.y - p0.w * 0.5f;
    const float p2x0 = p0.x + p0.z * 0.5f, p2y0 = p0.y + p0.w * 0.5f;
    const float pa0  = p0.z * p0.w;                    // area_p (no eps)
    const float p1x1 = p1.x - p1.z * 0.5f, p1y1 = p1.y - p1.w * 0.5f;
    const float p2x1 = p1.x + p1.z * 0.5f, p2y1 = p1.y + p1.w * 0.5f;
    const float pa1  = p1.z * p1.w;

    // Hot loop: pos <=> exists k with iou_k > 0.5
    //   iou>0.5 <=> 2*inter > pa+ga-inter+1e-6 <=> 3*inter - (ga+1e-6) > pa
    // Track m = max_k(3*inter - thr_k); pos <=> m > pa. 11 VALU/pair,
    // GT operands are SGPRs (uniform s_load of gp[]). ngt==0 -> m=-inf -> neg.
    float m0 = -1e30f, m1 = -1e30f;
    auto step = [&](int k) {
        const float g1x = gp[k * 8 + 0], g1y = gp[k * 8 + 1];
        const float g2x = gp[k * 8 + 2], g2y = gp[k * 8 + 3];
        const float thr = gp[k * 8 + 4];
        const float wx0 = fmaxf(fminf(p2x0, g2x) - fmaxf(p1x0, g1x), 0.0f);
        const float wy0 = fmaxf(fminf(p2y0, g2y) - fmaxf(p1y0, g1y), 0.0f);
        const float wx1 = fmaxf(fminf(p2x1, g2x) - fmaxf(p1x1, g1x), 0.0f);
        const float wy1 = fmaxf(fminf(p2y1, g2y) - fmaxf(p1y1, g1y), 0.0f);
        m0 = fmaxf(m0, fmaf(3.0f, wx0 * wy0, -thr));
        m1 = fmaxf(m1, fmaf(3.0f, wx1 * wy1, -thr));
    };
    if (ngt == 20) {
        #pragma unroll
        for (int k = 0; k < 20; ++k) step(k);
    } else {
        for (int k = 0; k < ngt; ++k) step(k);
    }

    float pos_cnt = 0.f, neg_cnt = 0.f;
    float box_acc = 0.f, spp_acc = 0.f, spn_acc = 0.f, ce_acc = 0.f;

    // Rare positive path: exact argmax (first-max, ascending k) + losses.
    auto handle = [&](bool valid, float m, float pa, const float4& p,
                      float p1x, float p1y, float p2x, float p2y,
                      float o, int idx) {
        if (!valid) return;
        if (m > pa) {                     // positive (rare ~0.1%)
            pos_cnt += 1.0f;
            float best = -1.0f; int bk = 0;
            for (int k = 0; k < ngt; ++k) {
                const float wx = fmaxf(fminf(p2x, gp[k*8+2]) - fmaxf(p1x, gp[k*8+0]), 0.0f);
                const float wy = fmaxf(fminf(p2y, gp[k*8+3]) - fmaxf(p1y, gp[k*8+1]), 0.0f);
                const float inter = wx * wy;
                const float den = pa + (gp[k*8+4] - inter);   // pa+ga-inter+1e-6
                const float iou = inter / den;
                if (iou > best) { best = iou; bk = k; }
            }
            const int gi = min(max(start + bk, 0), total_gt - 1);
            const float4 gb = ((const float4*)gt_boxes)[gi];
            const float dx = p.x - gb.x, dy = p.y - gb.y;
            const float dz = p.z - gb.z, dw = p.w - gb.w;
            box_acc += dx * dx + dy * dy + dz * dz + dw * dw;
            spp_acc += softplus_f(-o);
            const float* lg = pred_labels + (size_t)idx * C_;
            float mx = lg[0];
            #pragma unroll
            for (int i = 1; i < C_; ++i) mx = fmaxf(mx, lg[i]);
            float sexp = 0.f;
            #pragma unroll
            for (int i = 0; i < C_; ++i) sexp += expf(lg[i] - mx);
            ce_acc += -(lg[gt_labels[gi]] - mx - logf(sexp));
        } else {
            neg_cnt += 1.0f;
            spn_acc += softplus_f(o);
        }
    };
    handle(v0, m0, pa0, p0, p1x0, p1y0, p2x0, p2y0, o0, idx0);
    handle(v1, m1, pa1, p1, p1x1, p1y1, p2x1, p2y1, o1, idx1);

    // block reduction of 6 values
    float v[6] = {pos_cnt, neg_cnt, box_acc, spp_acc, spn_acc, ce_acc};
    #pragma unroll
    for (int i = 0; i < 6; ++i) {
        float x = v[i];
        for (int s = 32; s; s >>= 1) x += __shfl_down(x, s, 64);
        v[i] = x;
    }
    if ((tid & 63) == 0) {
        const int w = tid >> 6;
        #pragma unroll
        for (int i = 0; i < 6; ++i) s_red[w][i] = v[i];
    }
    __syncthreads();
    if (tid == 0) {
        float* outp = partials + (size_t)(cam * NCHUNK + chunk) * 8;
        #pragma unroll
        for (int i = 0; i < 6; ++i)
            outp[i] = s_red[0][i] + s_red[1][i] + s_red[2][i] + s_red[3][i];
    }
}

// ---------------- phase 2 ----------------
__global__ void yolo_phase2(const float* __restrict__ partials,
                            float* __restrict__ out)
{
    const int t = threadIdx.x;   // 0..63
    float box_sum = 0.f, obj_sum = 0.f, noobj_sum = 0.f, cls_sum = 0.f;
    float np_ = 0.f, nn_ = 0.f;

    if (t < NCAMS) {
        float pp = 0.f, n = 0.f, bx = 0.f, sp = 0.f, sn = 0.f, ce = 0.f;
        for (int h = 0; h < NCHUNK; ++h) {
            const float* q = partials + (size_t)(t * NCHUNK + h) * 8;
            pp += q[0]; n  += q[1]; bx += q[2];
            sp += q[3]; sn += q[4]; ce += q[5];
        }
        box_sum   = L_COORD * bx;
        obj_sum   = (pp > 0.f) ? sp / fmaxf(pp, 1.0f) : 0.f;
        cls_sum   = (pp > 0.f) ? ce / fmaxf(pp, 1.0f) : 0.f;
        noobj_sum = L_NOOBJ * ((n > 0.f) ? sn / fmaxf(n, 1.0f) : 0.f);
        np_ = pp; nn_ = n;
    }
    for (int s = 32; s; s >>= 1) {
        box_sum   += __shfl_down(box_sum, s, 64);
        obj_sum   += __shfl_down(obj_sum, s, 64);
        noobj_sum += __shfl_down(noobj_sum, s, 64);
        cls_sum   += __shfl_down(cls_sum, s, 64);
        np_       += __shfl_down(np_, s, 64);
        nn_       += __shfl_down(nn_, s, 64);
    }
    if (t == 0) {
        const float box_loss   = (np_ > 0.f) ? box_sum / fmaxf(np_, 1.0f) : 0.f;
        const float obj_loss   = (np_ > 0.f) ? obj_sum / fmaxf(np_, 1.0f) : 0.f;
        const float cls_loss   = (np_ > 0.f) ? cls_sum / fmaxf(np_, 1.0f) : 0.f;
        const float noobj_loss = (nn_ > 0.f) ? noobj_sum / fmaxf(nn_, 1.0f) : 0.f;
        const float total = box_loss + obj_loss + noobj_loss + cls_loss;
        out[0] = total;
        out[1] = box_loss;
        out[2] = obj_loss;
        out[3] = noobj_loss;
        out[4] = cls_loss;
    }
}

extern "C" void kernel_launch(void* const* d_in, const int* in_sizes, int n_in,
                              void* d_out, int out_size, void* d_ws, size_t ws_size,
                              hipStream_t stream) {
    const float* pred_boxes  = (const float*)d_in[0];
    const float* pred_labels = (const float*)d_in[1];
    const float* pred_obj    = (const float*)d_in[2];
    const float* gt_boxes    = (const float*)d_in[3];
    const int*   gt_labels   = (const int*)d_in[4];
    const int*   se          = (const int*)d_in[5];
    const int total_gt = in_sizes[3] / 4;

    // ws layout: partials | gtprep | gtmeta
    float* partials = (float*)d_ws;                          // 48*50*8 f = 76.8 KB
    float* gtprep   = partials + (size_t)NCAMS * NCHUNK * 8; // 48*32*8 f = 49 KB
    int*   gtmeta   = (int*)(gtprep + (size_t)NCAMS * MAXGT * 8);

    yolo_prep<<<(NCAMS * 32 + 255) / 256, 256, 0, stream>>>(
        gt_boxes, se, total_gt, gtprep, gtmeta);

    dim3 grid(NCHUNK, NCAMS);
    yolo_phase1<<<grid, BLOCK, 0, stream>>>(pred_boxes, pred_labels, pred_obj,
                                            gt_boxes, gt_labels,
                                            gtprep, gtmeta, total_gt, partials);
    yolo_phase2<<<1, 64, 0, stream>>>(partials, (float*)d_out);
}

// Round 5
// 127.763 us; speedup vs baseline: 1.0412x; 1.0412x over previous
//
#include <hip/hip_runtime.h>
#include <math.h>

// Problem constants (from reference)
#define NCAMS 48      // B*NC = 8*6
#define NC_   6
#define A_    25200
#define C_    10
#define MAXGT 32
#define L_COORD 5.0f
#define L_NOOBJ 0.5f

// 4 anchors/thread -> 1200 blocks. GT staged in LDS per block (cheap, ≤32
// threads). Hot loop = 11 VALU ops per (anchor,GT) pair, no div/rcp, no
// argmax: positives (~0.1%) re-run exact argmax in a divergent epilogue.
#define BLOCK  256
#define APT    4
#define CHUNK  (BLOCK * APT)                 // 1024
#define NCHUNK ((A_ + CHUNK - 1) / CHUNK)    // 25

__device__ __forceinline__ float softplus_f(float x) {
    return fmaxf(x, 0.0f) + log1pf(expf(-fabsf(x)));
}

__global__ __launch_bounds__(BLOCK)
void yolo_phase1(const float* __restrict__ pred_boxes,   // (cams, A, 4)
                 const float* __restrict__ pred_labels,  // (cams, A, C)
                 const float* __restrict__ pred_obj,     // (cams, A, 1)
                 const float* __restrict__ gt_boxes,     // (TG, 4)
                 const int*   __restrict__ gt_labels,    // (TG)
                 const int*   __restrict__ se,           // (B, NC)
                 int total_gt,
                 float* __restrict__ partials)           // (cams*NCHUNK, 8)
{
    const int cam   = blockIdx.y;
    const int chunk = blockIdx.x;
    const int tid   = threadIdx.x;

    __shared__ float4 s_g[MAXGT];     // g1x, g1y, g2x, g2y
    __shared__ float  s_thr[MAXGT];   // ga + 1e-6
    __shared__ float4 s_gb[MAXGT];    // original cxcywh (epilogue)
    __shared__ int    s_lbl[MAXGT];
    __shared__ float  s_red[BLOCK / 64][6];

    // uniform per block: start / ngt (scalar ops, se is 48 ints in L1)
    const int b  = cam / NC_;
    const int nc = cam - b * NC_;
    int off = 0;
    for (int bb = 0; bb < b; ++bb) off += se[bb * NC_ + (NC_ - 1)];
    const int start = off + (nc ? se[b * NC_ + nc - 1] : 0);
    const int end   = off + se[b * NC_ + nc];
    int ngt = end - start;
    ngt = min(max(ngt, 0), MAXGT);

    if (tid < ngt) {
        const int gi = min(max(start + tid, 0), total_gt - 1);  // ref clips
        const float4 gb = ((const float4*)gt_boxes)[gi];
        const float hw = gb.z * 0.5f, hh = gb.w * 0.5f;
        s_g[tid]   = make_float4(gb.x - hw, gb.y - hh, gb.x + hw, gb.y + hh);
        s_thr[tid] = gb.z * gb.w + 1e-6f;
        s_gb[tid]  = gb;
        s_lbl[tid] = gt_labels[gi];
    }
    __syncthreads();

    const int base = chunk * CHUNK;
    const float4* pb4 = (const float4*)pred_boxes;

    bool  valid[APT];
    int   aidx[APT];
    float p1x[APT], p1y[APT], p2x[APT], p2y[APT], pa[APT], o[APT], m[APT];

    #pragma unroll
    for (int j = 0; j < APT; ++j) {
        const int a = base + j * BLOCK + tid;
        valid[j] = (a < A_);
        const int idx = cam * A_ + (valid[j] ? a : (A_ - 1));
        aidx[j] = idx;
        const float4 p = pb4[idx];      // p itself not kept live (epilogue reloads)
        o[j] = pred_obj[idx];
        const float hw = p.z * 0.5f, hh = p.w * 0.5f;
        p1x[j] = p.x - hw; p1y[j] = p.y - hh;
        p2x[j] = p.x + hw; p2y[j] = p.y + hh;
        pa[j]  = p.z * p.w;             // area_p (no eps; eps lives in thr)
        m[j]   = -1e30f;
    }

    // Screen: pos <=> exists k: iou_k > 0.5
    //   iou>0.5 <=> 2*inter > pa+ga-inter+1e-6 <=> 3*inter-(ga+1e-6) > pa
    // Track m = max_k fma(3,inter,-thr_k); pos <=> m > pa.
    // One ds_read_b128 + ds_read_b32 per k serves all 4 anchors.
    auto step = [&](int k) {
        const float4 g  = s_g[k];
        const float thr = s_thr[k];
        #pragma unroll
        for (int j = 0; j < APT; ++j) {
            const float wx = fmaxf(fminf(p2x[j], g.z) - fmaxf(p1x[j], g.x), 0.0f);
            const float wy = fmaxf(fminf(p2y[j], g.w) - fmaxf(p1y[j], g.y), 0.0f);
            m[j] = fmaxf(m[j], fmaf(3.0f, wx * wy, -thr));
        }
    };
    if (ngt == 20) {                  // dataset hot path; bounded unroll
        #pragma unroll 5
        for (int k = 0; k < 20; ++k) step(k);
    } else {
        for (int k = 0; k < ngt; ++k) step(k);
    }

    float pos_cnt = 0.f, neg_cnt = 0.f;
    float box_acc = 0.f, spp_acc = 0.f, spn_acc = 0.f, ce_acc = 0.f;

    #pragma unroll
    for (int j = 0; j < APT; ++j) {
        if (!valid[j]) continue;
        if (m[j] > pa[j]) {           // positive: rare (~0.1%), exact path
            pos_cnt += 1.0f;
            float best = -1.0f; int bk = 0;
            for (int k = 0; k < ngt; ++k) {   // jnp.argmax: strict '>', asc k
                const float4 g = s_g[k];
                const float wx = fmaxf(fminf(p2x[j], g.z) - fmaxf(p1x[j], g.x), 0.0f);
                const float wy = fmaxf(fminf(p2y[j], g.w) - fmaxf(p1y[j], g.y), 0.0f);
                const float inter = wx * wy;
                const float iou = inter / (pa[j] + (s_thr[k] - inter));
                if (iou > best) { best = iou; bk = k; }
            }
            const float4 p  = pb4[aidx[j]];   // reload (L2 hit, rare)
            const float4 gb = s_gb[bk];
            const float dx = p.x - gb.x, dy = p.y - gb.y;
            const float dz = p.z - gb.z, dw = p.w - gb.w;
            box_acc += dx * dx + dy * dy + dz * dz + dw * dw;
            spp_acc += softplus_f(-o[j]);
            const float* lg = pred_labels + (size_t)aidx[j] * C_;
            float mx = lg[0];
            #pragma unroll
            for (int i = 1; i < C_; ++i) mx = fmaxf(mx, lg[i]);
            float sexp = 0.f;
            #pragma unroll
            for (int i = 0; i < C_; ++i) sexp += expf(lg[i] - mx);
            ce_acc += -(lg[s_lbl[bk]] - mx - logf(sexp));
        } else {
            neg_cnt += 1.0f;
            spn_acc += softplus_f(o[j]);
        }
    }

    // block reduction of 6 values
    float v[6] = {pos_cnt, neg_cnt, box_acc, spp_acc, spn_acc, ce_acc};
    #pragma unroll
    for (int i = 0; i < 6; ++i) {
        float x = v[i];
        for (int s = 32; s; s >>= 1) x += __shfl_down(x, s, 64);
        v[i] = x;
    }
    if ((tid & 63) == 0) {
        const int w = tid >> 6;
        #pragma unroll
        for (int i = 0; i < 6; ++i) s_red[w][i] = v[i];
    }
    __syncthreads();
    if (tid == 0) {
        float* outp = partials + (size_t)(cam * NCHUNK + chunk) * 8;
        #pragma unroll
        for (int i = 0; i < 6; ++i)
            outp[i] = s_red[0][i] + s_red[1][i] + s_red[2][i] + s_red[3][i];
    }
}

__global__ void yolo_phase2(const float* __restrict__ partials,
                            float* __restrict__ out)
{
    const int t = threadIdx.x;   // 0..63
    float box_sum = 0.f, obj_sum = 0.f, noobj_sum = 0.f, cls_sum = 0.f;
    float np_ = 0.f, nn_ = 0.f;

    if (t < NCAMS) {
        float pp = 0.f, n = 0.f, bx = 0.f, sp = 0.f, sn = 0.f, ce = 0.f;
        for (int h = 0; h < NCHUNK; ++h) {
            const float* q = partials + (size_t)(t * NCHUNK + h) * 8;
            pp += q[0]; n  += q[1]; bx += q[2];
            sp += q[3]; sn += q[4]; ce += q[5];
        }
        box_sum   = L_COORD * bx;
        obj_sum   = (pp > 0.f) ? sp / fmaxf(pp, 1.0f) : 0.f;
        cls_sum   = (pp > 0.f) ? ce / fmaxf(pp, 1.0f) : 0.f;
        noobj_sum = L_NOOBJ * ((n > 0.f) ? sn / fmaxf(n, 1.0f) : 0.f);
        np_ = pp; nn_ = n;
    }
    for (int s = 32; s; s >>= 1) {
        box_sum   += __shfl_down(box_sum, s, 64);
        obj_sum   += __shfl_down(obj_sum, s, 64);
        noobj_sum += __shfl_down(noobj_sum, s, 64);
        cls_sum   += __shfl_down(cls_sum, s, 64);
        np_       += __shfl_down(np_, s, 64);
        nn_       += __shfl_down(nn_, s, 64);
    }
    if (t == 0) {
        const float box_loss   = (np_ > 0.f) ? box_sum / fmaxf(np_, 1.0f) : 0.f;
        const float obj_loss   = (np_ > 0.f) ? obj_sum / fmaxf(np_, 1.0f) : 0.f;
        const float cls_loss   = (np_ > 0.f) ? cls_sum / fmaxf(np_, 1.0f) : 0.f;
        const float noobj_loss = (nn_ > 0.f) ? noobj_sum / fmaxf(nn_, 1.0f) : 0.f;
        const float total = box_loss + obj_loss + noobj_loss + cls_loss;
        out[0] = total;
        out[1] = box_loss;
        out[2] = obj_loss;
        out[3] = noobj_loss;
        out[4] = cls_loss;
    }
}

extern "C" void kernel_launch(void* const* d_in, const int* in_sizes, int n_in,
                              void* d_out, int out_size, void* d_ws, size_t ws_size,
                              hipStream_t stream) {
    const float* pred_boxes  = (const float*)d_in[0];
    const float* pred_labels = (const float*)d_in[1];
    const float* pred_obj    = (const float*)d_in[2];
    const float* gt_boxes    = (const float*)d_in[3];
    const int*   gt_labels   = (const int*)d_in[4];
    const int*   se          = (const int*)d_in[5];
    const int total_gt = in_sizes[3] / 4;

    float* partials = (float*)d_ws;   // 48*25*8 floats = 38.4 KB

    dim3 grid(NCHUNK, NCAMS);
    yolo_phase1<<<grid, BLOCK, 0, stream>>>(pred_boxes, pred_labels, pred_obj,
                                            gt_boxes, gt_labels, se,
                                            total_gt, partials);
    yolo_phase2<<<1, 64, 0, stream>>>(partials, (float*)d_out);
}